// Round 13
// baseline (802.540 us; speedup 1.0000x reference)
//
#include <hip/hip_runtime.h>
#include <hip/hip_bf16.h>
#include <stdint.h>
#include <stddef.h>

typedef __attribute__((ext_vector_type(8))) short short8;
typedef __attribute__((ext_vector_type(4))) float f32x4;
typedef __attribute__((ext_vector_type(16))) float f32x16;

#define NB 2048
#define HD 512
#define SD 256

#define AROW 516   // shorts per s-row (512 k + 4 pad): bank step 258%32=2 ->
                   // 2 lanes/bank on all b128 reads/writes = conflict-free

__device__ __forceinline__ short f2bf(float x) {
  __hip_bfloat16 h = __float2bfloat16(x);
  return *reinterpret_cast<short*>(&h);
}

__device__ __forceinline__ float fast_tanh(float x) {
  x = fminf(fmaxf(x, -15.f), 15.f);
  float e = __expf(2.f * x);
  return __fdividef(e - 1.f, e + 1.f);
}

// ---- Wtb16[kb][j][kk] = bf16(W[kb*16+kk][j]), kb in [0,32) ----
__global__ __launch_bounds__(256) void wconv_kernel(const float* __restrict__ W,
                                                    short* __restrict__ Wtb16) {
  __shared__ float tile[32][33];
  const int bx = blockIdx.x;
  const int tk0 = (bx & 15) * 32;
  const int tj0 = (bx >> 4) * 32;
  const int lx = threadIdx.x & 31;
  const int ly = threadIdx.x >> 5;
  for (int r = 0; r < 4; ++r) {
    int yy = ly + r * 8;
    tile[yy][lx] = W[(size_t)(tk0 + yy) * HD + tj0 + lx];
  }
  __syncthreads();
  for (int r = 0; r < 4; ++r) {
    int yy = ly + r * 8;
    const int k = tk0 + lx;
    Wtb16[(size_t)(k >> 4) * (HD * 16) + (size_t)(tj0 + yy) * 16 + (k & 15)] =
        f2bf(tile[lx][yy]);
  }
}

// ---- alignment[n][s] = sum_j tanh( sum_k hs[n,k,s]*W[k,j] + b[j] ) * c[j] ----
// Block = 64 s x FULL 512 j, 512 threads = 8 waves (disjoint 64-j strips).
// A-panel (64s x 512k bf16, 66 KB LDS) split into 4 k-sub-panels of 128.
// Software pipeline per iteration p:
//   MFMA(panel p)                      [reads LDS cols p*128..+127, no writes]
//   pack+ds_write(panel p+1)           [raw loads issued one panel ago ->
//                                       the vmcnt wait here IS the HBM pacing]
//   issue raw loads(panel p+2)         [keeps >=1 panel in the HBM queue]
//   __syncthreads()                    [publishes panel p+1]
// -> HBM stream is continuous; MFMA + W-L2 ring ride underneath. Per-CU cost
// ~= staging floor (128 KB / 10.25 B/cyc = 12.8 K cyc per block).
__global__ void __launch_bounds__(512, 2)
align_kernel(const float* __restrict__ hs, const short* __restrict__ Wtb16,
             const float* __restrict__ bias, const float* __restrict__ ctxv,
             float* __restrict__ align_out)
{
  __shared__ short As[64 * AROW];   // 66 KB
  __shared__ float abuf[64];

  const int tid = threadIdx.x;
  const int n = blockIdx.x >> 2;
  const int s0 = (blockIdx.x & 3) * 64;
  const float* hsn = hs + (size_t)n * (HD * SD) + s0;

  if (tid < 64) abuf[tid] = 0.f;

  // staging map: thread -> (s = tid&63, 16-k slice tid>>6 within each panel)
  const int a_s = tid & 63;
  const int kbase = (tid >> 6) * 16;          // 0..112
  const float* aSrc = hsn + a_s + (size_t)kbase * SD;  // + (p*128+e)*SD
  short* aDstRow = &As[a_s * AROW + kbase];            // + p*128

  // MFMA lane map
  const int lane = tid & 63;
  const int wid = tid >> 6;
  const int jb = wid * 64;
  const int l31 = lane & 31;
  const int hg = lane >> 5;                   // k-half: k = hg*8 + e
  const short* wlane = Wtb16 + (size_t)(jb + l31) * 16 + hg * 8;
  const int afo = l31 * AROW + hg * 8;

  float ra[16];

  // ---- prologue: issue panel 0, fill W ring, pack 0, issue panel 1 ----
  #pragma unroll
  for (int e = 0; e < 16; ++e) ra[e] = aSrc[(size_t)e * SD];

  short8 wb[2][2];
  wb[0][0] = *(const short8*)(wlane);
  wb[0][1] = *(const short8*)(wlane + 32 * 16);
  wb[1][0] = *(const short8*)(wlane + (size_t)(HD * 16));
  wb[1][1] = *(const short8*)(wlane + (size_t)(HD * 16) + 32 * 16);

  {
    short8 pk0, pk1;
    #pragma unroll
    for (int e = 0; e < 8; ++e) { pk0[e] = f2bf(ra[e]); pk1[e] = f2bf(ra[8 + e]); }
    *(short8*)(aDstRow) = pk0;
    *(short8*)(aDstRow + 8) = pk1;
  }
  #pragma unroll
  for (int e = 0; e < 16; ++e) ra[e] = aSrc[(size_t)(128 + e) * SD];

  __syncthreads();

  f32x16 acc[2][2];
  #pragma unroll
  for (int i = 0; i < 2; ++i)
    #pragma unroll
    for (int p = 0; p < 2; ++p)
      #pragma unroll
      for (int q = 0; q < 16; ++q) acc[i][p][q] = 0.f;

  // ---- main pipeline over 4 k-sub-panels ----
  #pragma unroll
  for (int p = 0; p < 4; ++p) {
    // A-fragment ring for this panel (2-deep, in-panel)
    short8 ab[2][2];
    ab[0][0] = *(const short8*)&As[afo + p * 128];
    ab[0][1] = *(const short8*)&As[afo + 32 * AROW + p * 128];
    ab[1][0] = *(const short8*)&As[afo + p * 128 + 16];
    ab[1][1] = *(const short8*)&As[afo + 32 * AROW + p * 128 + 16];

    #pragma unroll
    for (int i = 0; i < 8; ++i) {
      const int kb = p * 8 + i;
      const int ws = kb & 1;
      const int as_ = i & 1;

      __builtin_amdgcn_s_setprio(1);
      acc[0][0] = __builtin_amdgcn_mfma_f32_32x32x16_bf16(wb[ws][0], ab[as_][0], acc[0][0], 0, 0, 0);
      acc[0][1] = __builtin_amdgcn_mfma_f32_32x32x16_bf16(wb[ws][1], ab[as_][0], acc[0][1], 0, 0, 0);
      acc[1][0] = __builtin_amdgcn_mfma_f32_32x32x16_bf16(wb[ws][0], ab[as_][1], acc[1][0], 0, 0, 0);
      acc[1][1] = __builtin_amdgcn_mfma_f32_32x32x16_bf16(wb[ws][1], ab[as_][1], acc[1][1], 0, 0, 0);
      __builtin_amdgcn_s_setprio(0);

      if (kb < 30) {  // refill W ring slot for kb+2
        const short* wk = wlane + (size_t)(kb + 2) * (HD * 16);
        wb[ws][0] = *(const short8*)(wk);
        wb[ws][1] = *(const short8*)(wk + 32 * 16);
      }
      if (i < 6) {    // refill A ring slot for local kb i+2 (same panel)
        ab[as_][0] = *(const short8*)&As[afo + p * 128 + (i + 2) * 16];
        ab[as_][1] = *(const short8*)&As[afo + 32 * AROW + p * 128 + (i + 2) * 16];
      }
    }

    // stage panel p+1 (raw loads issued one panel ago -> HBM-paced wait),
    // then issue raw loads for panel p+2
    if (p < 3) {
      short8 pk0, pk1;
      #pragma unroll
      for (int e = 0; e < 8; ++e) { pk0[e] = f2bf(ra[e]); pk1[e] = f2bf(ra[8 + e]); }
      *(short8*)(aDstRow + (p + 1) * 128) = pk0;
      *(short8*)(aDstRow + (p + 1) * 128 + 8) = pk1;
      if (p < 2) {
        #pragma unroll
        for (int e = 0; e < 16; ++e)
          ra[e] = aSrc[(size_t)((p + 2) * 128 + e) * SD];
      }
      __syncthreads();
    }
  }

  // ---- epilogue: D col = s = l31 (+i*32), row(q) = (q&3)+8*(q>>2)+4*hg (+p*32)
  float part0 = 0.f, part1 = 0.f;
  #pragma unroll
  for (int p = 0; p < 2; ++p) {
    const int jfr = jb + p * 32 + hg * 4;
    #pragma unroll
    for (int g = 0; g < 4; ++g) {
      const int j4 = jfr + g * 8;
      f32x4 bv = *(const f32x4*)(bias + j4);
      f32x4 cv = *(const f32x4*)(ctxv + j4);
      #pragma unroll
      for (int r = 0; r < 4; ++r) {
        const int q = g * 4 + r;
        part0 += fast_tanh(acc[0][p][q] + bv[r]) * cv[r];
        part1 += fast_tanh(acc[1][p][q] + bv[r]) * cv[r];
      }
    }
  }
  part0 += __shfl_xor(part0, 32);
  part1 += __shfl_xor(part1, 32);
  if (lane < 32) {
    atomicAdd(&abuf[l31], part0);
    atomicAdd(&abuf[32 + l31], part1);
  }
  __syncthreads();
  if (tid < 64) align_out[(size_t)n * SD + s0 + tid] = abuf[tid];
}

// ---- softmax over s + context[n,h] = sum_s attn[s]*hs[n,h,s] ----
__global__ __launch_bounds__(256) void ctx_kernel(const float* __restrict__ hs,
                                                  const float* __restrict__ align_in,
                                                  float* __restrict__ out)
{
  __shared__ __align__(16) float attn_s[256];
  __shared__ float red[8];
  const int n = blockIdx.x;
  const int t = threadIdx.x;
  const int lane = t & 63, wid = t >> 6;

  float a = align_in[(size_t)n * 256 + t];
  float m = a;
  #pragma unroll
  for (int off = 32; off; off >>= 1) m = fmaxf(m, __shfl_xor(m, off));
  if (lane == 0) red[wid] = m;
  __syncthreads();
  m = fmaxf(fmaxf(red[0], red[1]), fmaxf(red[2], red[3]));
  float e = __expf(a - m);
  float s = e;
  #pragma unroll
  for (int off = 32; off; off >>= 1) s += __shfl_xor(s, off);
  if (lane == 0) red[4 + wid] = s;
  __syncthreads();
  s = red[4] + red[5] + red[6] + red[7];
  attn_s[t] = e / s;
  __syncthreads();

  const int grp = t & 7;      // s-chunk of 32
  const int hrow = t >> 3;    // 0..31
  float av[32];
  #pragma unroll
  for (int u = 0; u < 8; ++u) {
    float4 v = *(const float4*)&attn_s[grp * 32 + u * 4];
    av[4*u+0] = v.x; av[4*u+1] = v.y; av[4*u+2] = v.z; av[4*u+3] = v.w;
  }
  const float* hb = hs + (size_t)n * (HD * SD) + grp * 32;
  for (int it = 0; it < 16; ++it) {
    const int h = it * 32 + hrow;
    const float4* p = (const float4*)(hb + (size_t)h * SD);
    float acc = 0.f;
    #pragma unroll
    for (int u = 0; u < 8; ++u) {
      float4 v = p[u];
      acc += av[4*u+0]*v.x + av[4*u+1]*v.y + av[4*u+2]*v.z + av[4*u+3]*v.w;
    }
    acc += __shfl_xor(acc, 1);
    acc += __shfl_xor(acc, 2);
    acc += __shfl_xor(acc, 4);
    if (grp == 0) out[(size_t)n * HD + h] = acc;
  }
}

extern "C" void kernel_launch(void* const* d_in, const int* in_sizes, int n_in,
                              void* d_out, int out_size, void* d_ws, size_t ws_size,
                              hipStream_t stream) {
  (void)in_sizes; (void)n_in; (void)out_size; (void)ws_size;
  const float* hs = (const float*)d_in[0];
  const float* W  = (const float*)d_in[1];
  const float* b  = (const float*)d_in[2];
  const float* c  = (const float*)d_in[3];
  float* out = (float*)d_out;

  float* align_ws = (float*)d_ws;                                  // 2 MB
  short* Wtb16 = (short*)((char*)d_ws + (size_t)NB * SD * 4);      // 512 KB

  wconv_kernel<<<256, 256, 0, stream>>>(W, Wtb16);
  align_kernel<<<NB * 4, 512, 0, stream>>>(hs, Wtb16, b, c, align_ws);
  ctx_kernel<<<NB, 256, 0, stream>>>(hs, align_ws, out);
}